// Round 1
// baseline (423.094 us; speedup 1.0000x reference)
//
#include <hip/hip_runtime.h>

constexpr int Bb = 2, Cc = 512, Nn = 3072, Hh = 8, Dd = 64;
constexpr int BN = Bb * Nn;

typedef __bf16 bf16;
typedef __attribute__((ext_vector_type(8))) __bf16 bf16x8;
typedef __attribute__((ext_vector_type(4))) float f32x4;

#define DEVINL static __device__ __forceinline__

DEVINL bf16x8 ldb8(const bf16* p) { return *reinterpret_cast<const bf16x8*>(p); }

// ---------------- 1. transpose + cast x [B,C,N] -> feats [B,N,C] bf16 ----------------
__global__ void k_tx(const float* __restrict__ x, bf16* __restrict__ feats) {
    __shared__ float t[32][33];
    const int b = blockIdx.z;
    const int n0 = blockIdx.x * 32, c0 = blockIdx.y * 32;
    const int tx = threadIdx.x, ty = threadIdx.y;   // 32 x 8
#pragma unroll
    for (int i = 0; i < 4; ++i)
        t[ty + i * 8][tx] = x[((size_t)b * Cc + c0 + ty + i * 8) * Nn + n0 + tx];
    __syncthreads();
#pragma unroll
    for (int i = 0; i < 4; ++i)
        feats[((size_t)b * Nn + n0 + ty + i * 8) * Cc + c0 + tx] = (bf16)t[tx][ty + i * 8];
}

// ---------------- 2. pack weights to bf16 ----------------
__global__ void k_packw(const float* __restrict__ Wq, const float* __restrict__ Wk,
                        const float* __restrict__ Wv, const float* __restrict__ Wo,
                        bf16* __restrict__ Wqkv, bf16* __restrict__ WoB) {
    const int i = blockIdx.x * 256 + threadIdx.x;   // 0 .. 512*512-1
    Wqkv[i]              = (bf16)Wq[i];
    Wqkv[i + 262144]     = (bf16)Wk[i];
    Wqkv[i + 524288]     = (bf16)Wv[i];
    WoB[i]               = (bf16)Wo[i];
}

// ---------------- 3. fused mask+bias -> bf16 ----------------
__global__ void k_biasm(const int* __restrict__ adj, const float* __restrict__ gb,
                        bf16* __restrict__ biasm) {
    const size_t i = (size_t)blockIdx.x * 256 + threadIdx.x;
    biasm[i] = adj[i] ? (bf16)gb[i] : (bf16)(-1e30f);
}

// ---------------- 4. QKV GEMM: feats[BN,512] x Wqkv[1536,512]^T -> Q,K [B,H,N,D], Vt [B,H,D,N]
__global__ __launch_bounds__(256) void k_qkv(
        const bf16* __restrict__ feats, const bf16* __restrict__ Wqkv,
        const float* __restrict__ bq, const float* __restrict__ bk, const float* __restrict__ bv,
        bf16* __restrict__ Q, bf16* __restrict__ K, bf16* __restrict__ Vt) {
    const int m0 = blockIdx.x * 64;
    const int n0 = blockIdx.y * 64;
    const int tid = threadIdx.x, w = tid >> 6, lane = tid & 63;
    const int lg = lane >> 4, lc = lane & 15;

    f32x4 acc[4];
    const f32x4 z4 = {0.f, 0.f, 0.f, 0.f};
#pragma unroll
    for (int jt = 0; jt < 4; ++jt) acc[jt] = z4;

    const bf16* arow = feats + (size_t)(m0 + w * 16 + lc) * Cc;
#pragma unroll 4
    for (int ks = 0; ks < 16; ++ks) {
        bf16x8 a = ldb8(arow + ks * 32 + lg * 8);
#pragma unroll
        for (int jt = 0; jt < 4; ++jt) {
            bf16x8 bb = ldb8(Wqkv + (size_t)(n0 + jt * 16 + lc) * Cc + ks * 32 + lg * 8);
            acc[jt] = __builtin_amdgcn_mfma_f32_16x16x32_bf16(a, bb, acc[jt], 0, 0, 0);
        }
    }

    const int proj = n0 >> 9;            // 0=q 1=k 2=v
    const int head = (n0 >> 6) & 7;
    const float* bias = proj == 0 ? bq : (proj == 1 ? bk : bv);
#pragma unroll
    for (int jt = 0; jt < 4; ++jt) {
        const int dcol = jt * 16 + lc;   // 0..63 == d within head
        const float bs = bias[(n0 & 511) + dcol];
#pragma unroll
        for (int r = 0; r < 4; ++r) {
            const int m = m0 + w * 16 + lg * 4 + r;
            const int b = m / Nn;
            const int n = m - b * Nn;
            const float v = acc[jt][r] + bs;
            if (proj == 0)
                Q[(((size_t)b * Hh + head) * Nn + n) * Dd + dcol] = (bf16)v;
            else if (proj == 1)
                K[(((size_t)b * Hh + head) * Nn + n) * Dd + dcol] = (bf16)v;
            else
                Vt[(((size_t)b * Hh + head) * Dd + dcol) * Nn + n] = (bf16)v;
        }
    }
}

// ---------------- 5. flash attention ----------------
__global__ __launch_bounds__(256) void k_attn(
        const bf16* __restrict__ Q, const bf16* __restrict__ K, const bf16* __restrict__ Vt,
        const bf16* __restrict__ biasm, bf16* __restrict__ att) {
    __shared__ bf16 sBias[64][72];
    __shared__ bf16 sP[4][16][72];

    const int i0 = blockIdx.x * 64;
    const int bh = blockIdx.y;                 // b*8+h
    const int b = bh >> 3, h = bh & 7;
    const int tid = threadIdx.x, w = tid >> 6, lane = tid & 63;
    const int lg = lane >> 4, lc = lane & 15;

    const bf16* Qb = Q  + (size_t)bh * Nn * Dd;
    const bf16* Kb = K  + (size_t)bh * Nn * Dd;
    const bf16* Vb = Vt + (size_t)bh * Dd * Nn;

    bf16x8 aq[2];
    {
        const bf16* qp = Qb + (size_t)(i0 + w * 16 + lc) * Dd + lg * 8;
        aq[0] = ldb8(qp);
        aq[1] = ldb8(qp + 32);
    }

    float mrow[4], lrow[4];
    f32x4 acc[4];
    const f32x4 z4 = {0.f, 0.f, 0.f, 0.f};
#pragma unroll
    for (int r = 0; r < 4; ++r) { mrow[r] = -1e30f; lrow[r] = 0.f; }
#pragma unroll
    for (int dj = 0; dj < 4; ++dj) acc[dj] = z4;

    for (int j0 = 0; j0 < Nn; j0 += 64) {
        __syncthreads();                       // prev-iter sBias/sP readers done
        // stage 64x64 bias tile (bf16x8 per task; 512 tasks / 256 threads)
        {
            int t = tid;
#pragma unroll
            for (int it = 0; it < 2; ++it, t += 256) {
                const int row = t >> 3, grp = t & 7;
                bf16x8 v = ldb8(biasm + (size_t)(i0 + row) * Nn + j0 + grp * 8);
                *reinterpret_cast<bf16x8*>(&sBias[row][grp * 8]) = v;
            }
        }
        // S = Q K^T  (16q x 64k per wave)
        f32x4 s[4];
#pragma unroll
        for (int jt = 0; jt < 4; ++jt) s[jt] = z4;
#pragma unroll
        for (int jt = 0; jt < 4; ++jt) {
            const bf16* kp = Kb + (size_t)(j0 + jt * 16 + lc) * Dd + lg * 8;
            bf16x8 b0 = ldb8(kp);
            bf16x8 b1 = ldb8(kp + 32);
            s[jt] = __builtin_amdgcn_mfma_f32_16x16x32_bf16(aq[0], b0, s[jt], 0, 0, 0);
            s[jt] = __builtin_amdgcn_mfma_f32_16x16x32_bf16(aq[1], b1, s[jt], 0, 0, 0);
        }
        __syncthreads();                       // sBias ready

        float sv[4][4];
        float tmax[4];
#pragma unroll
        for (int r = 0; r < 4; ++r) tmax[r] = -3.0e38f;
#pragma unroll
        for (int jt = 0; jt < 4; ++jt)
#pragma unroll
            for (int r = 0; r < 4; ++r) {
                float val = s[jt][r] * 0.125f + (float)sBias[w * 16 + lg * 4 + r][jt * 16 + lc];
                sv[jt][r] = val;
                tmax[r] = fmaxf(tmax[r], val);
            }
#pragma unroll
        for (int r = 0; r < 4; ++r) {
            float v = tmax[r];
            v = fmaxf(v, __shfl_xor(v, 1));
            v = fmaxf(v, __shfl_xor(v, 2));
            v = fmaxf(v, __shfl_xor(v, 4));
            v = fmaxf(v, __shfl_xor(v, 8));
            tmax[r] = v;
        }
        float scl[4];
#pragma unroll
        for (int r = 0; r < 4; ++r) {
            const float mn = fmaxf(mrow[r], tmax[r]);
            scl[r] = __expf(mrow[r] - mn);
            mrow[r] = mn;
        }
        float rsum[4] = {0.f, 0.f, 0.f, 0.f};
#pragma unroll
        for (int jt = 0; jt < 4; ++jt)
#pragma unroll
            for (int r = 0; r < 4; ++r) {
                float p = __expf(sv[jt][r] - mrow[r]);
                sv[jt][r] = p;
                rsum[r] += p;
            }
#pragma unroll
        for (int r = 0; r < 4; ++r) {
            float v = rsum[r];
            v += __shfl_xor(v, 1);
            v += __shfl_xor(v, 2);
            v += __shfl_xor(v, 4);
            v += __shfl_xor(v, 8);
            lrow[r] = lrow[r] * scl[r] + v;
#pragma unroll
            for (int dj = 0; dj < 4; ++dj) acc[dj][r] *= scl[r];
        }
        // write P (bf16) to per-wave LDS, q-row major
#pragma unroll
        for (int jt = 0; jt < 4; ++jt)
#pragma unroll
            for (int r = 0; r < 4; ++r)
                sP[w][lg * 4 + r][jt * 16 + lc] = (bf16)sv[jt][r];
        __syncthreads();                       // P visible (uniform barrier)

        // acc += P V   (A = P[16x32], B = Vt)
#pragma unroll
        for (int ks = 0; ks < 2; ++ks) {
            bf16x8 pa = *reinterpret_cast<const bf16x8*>(&sP[w][lc][ks * 32 + lg * 8]);
#pragma unroll
            for (int dj = 0; dj < 4; ++dj) {
                const bf16* vp = Vb + (size_t)(dj * 16 + lc) * Nn + j0 + ks * 32 + lg * 8;
                bf16x8 bv = ldb8(vp);
                acc[dj] = __builtin_amdgcn_mfma_f32_16x16x32_bf16(pa, bv, acc[dj], 0, 0, 0);
            }
        }
    }

#pragma unroll
    for (int r = 0; r < 4; ++r) {
        const float inv = 1.f / lrow[r];
        const int n = i0 + w * 16 + lg * 4 + r;
#pragma unroll
        for (int dj = 0; dj < 4; ++dj)
            att[((size_t)b * Nn + n) * Cc + h * 64 + dj * 16 + lc] = (bf16)(acc[dj][r] * inv);
    }
}

// ---------------- 6. out GEMM: att[BN,512] x Wo^T + bo -> out [B,C,N] ----------------
__global__ __launch_bounds__(256) void k_out(
        const bf16* __restrict__ att, const bf16* __restrict__ WoB,
        const float* __restrict__ bo, float* __restrict__ out) {
    const int m0 = blockIdx.x * 64;
    const int n0 = blockIdx.y * 64;
    const int tid = threadIdx.x, w = tid >> 6, lane = tid & 63;
    const int lg = lane >> 4, lc = lane & 15;

    f32x4 acc[4];
    const f32x4 z4 = {0.f, 0.f, 0.f, 0.f};
#pragma unroll
    for (int jt = 0; jt < 4; ++jt) acc[jt] = z4;

    const bf16* arow = att + (size_t)(m0 + w * 16 + lc) * Cc;
#pragma unroll 4
    for (int ks = 0; ks < 16; ++ks) {
        bf16x8 a = ldb8(arow + ks * 32 + lg * 8);
#pragma unroll
        for (int jt = 0; jt < 4; ++jt) {
            bf16x8 bb = ldb8(WoB + (size_t)(n0 + jt * 16 + lc) * Cc + ks * 32 + lg * 8);
            acc[jt] = __builtin_amdgcn_mfma_f32_16x16x32_bf16(a, bb, acc[jt], 0, 0, 0);
        }
    }

    const int m = m0 + w * 16 + lg * 4;   // 4 consecutive n per lane
    const int b = m / Nn;
    const int n = m - b * Nn;
#pragma unroll
    for (int jt = 0; jt < 4; ++jt) {
        const int col = n0 + jt * 16 + lc;
        const float bs = bo[col];
        f32x4 vv;
#pragma unroll
        for (int r = 0; r < 4; ++r) vv[r] = acc[jt][r] + bs;
        *reinterpret_cast<f32x4*>(&out[((size_t)b * Cc + col) * Nn + n]) = vv;
    }
}

// ---------------- launch ----------------
extern "C" void kernel_launch(void* const* d_in, const int* in_sizes, int n_in,
                              void* d_out, int out_size, void* d_ws, size_t ws_size,
                              hipStream_t stream) {
    (void)in_sizes; (void)n_in; (void)out_size; (void)ws_size;
    const float* x  = (const float*)d_in[0];
    const int*   adj= (const int*)d_in[1];
    const float* gb = (const float*)d_in[2];
    const float* Wq = (const float*)d_in[3];
    const float* bq = (const float*)d_in[4];
    const float* Wk = (const float*)d_in[5];
    const float* bk = (const float*)d_in[6];
    const float* Wv = (const float*)d_in[7];
    const float* bv = (const float*)d_in[8];
    const float* Wo = (const float*)d_in[9];
    const float* bo = (const float*)d_in[10];
    float* out = (float*)d_out;

    char* ws = (char*)d_ws;
    bf16* feats = (bf16*)(ws);                    // 6,291,456 B
    bf16* Wqkv  = (bf16*)(ws + 6291456);          // 1,572,864 B
    bf16* WoB   = (bf16*)(ws + 7864320);          //   524,288 B
    bf16* Qm    = (bf16*)(ws + 8388608);          // 6,291,456 B
    bf16* Km    = (bf16*)(ws + 14680064);         // 6,291,456 B
    bf16* Vt    = (bf16*)(ws + 20971520);         // 6,291,456 B
    bf16* att   = (bf16*)(ws + 27262976);         // 6,291,456 B
    bf16* biasm = (bf16*)(ws + 33554432);         // 18,874,368 B  (total 50 MB)

    k_tx   <<<dim3(Nn / 32, Cc / 32, Bb), dim3(32, 8), 0, stream>>>(x, feats);
    k_packw<<<dim3(1024), dim3(256), 0, stream>>>(Wq, Wk, Wv, Wo, Wqkv, WoB);
    k_biasm<<<dim3((Nn * Nn) / 256), dim3(256), 0, stream>>>(adj, gb, biasm);
    k_qkv  <<<dim3(BN / 64, 1536 / 64), dim3(256), 0, stream>>>(feats, Wqkv, bq, bk, bv, Qm, Km, Vt);
    k_attn <<<dim3(Nn / 64, Bb * Hh), dim3(256), 0, stream>>>(Qm, Km, Vt, biasm, att);
    k_out  <<<dim3(BN / 64, Cc / 64), dim3(256), 0, stream>>>(att, WoB, bo, out);
}

// Round 2
// 416.980 us; speedup vs baseline: 1.0147x; 1.0147x over previous
//
#include <hip/hip_runtime.h>

constexpr int Bb = 2, Cc = 512, Nn = 3072, Hh = 8, Dd = 64;
constexpr int BN = Bb * Nn;
constexpr int NT = Nn / 64;   // 48 tiles per dim

typedef __bf16 bf16;
typedef __attribute__((ext_vector_type(8))) __bf16 bf16x8;
typedef __attribute__((ext_vector_type(4))) float f32x4;

#define DEVINL static __device__ __forceinline__

DEVINL bf16x8 ldb8(const bf16* p) { return *reinterpret_cast<const bf16x8*>(p); }

// ---------------- 1. transpose + cast x [B,C,N] -> feats [B,N,C] bf16 ----------------
__global__ void k_tx(const float* __restrict__ x, bf16* __restrict__ feats) {
    __shared__ float t[32][33];
    const int b = blockIdx.z;
    const int n0 = blockIdx.x * 32, c0 = blockIdx.y * 32;
    const int tx = threadIdx.x, ty = threadIdx.y;   // 32 x 8
#pragma unroll
    for (int i = 0; i < 4; ++i)
        t[ty + i * 8][tx] = x[((size_t)b * Cc + c0 + ty + i * 8) * Nn + n0 + tx];
    __syncthreads();
#pragma unroll
    for (int i = 0; i < 4; ++i)
        feats[((size_t)b * Nn + n0 + ty + i * 8) * Cc + c0 + tx] = (bf16)t[tx][ty + i * 8];
}

// ---------------- 2. pack weights to bf16 ----------------
__global__ void k_packw(const float* __restrict__ Wq, const float* __restrict__ Wk,
                        const float* __restrict__ Wv, const float* __restrict__ Wo,
                        bf16* __restrict__ Wqkv, bf16* __restrict__ WoB) {
    const int i = blockIdx.x * 256 + threadIdx.x;   // 0 .. 512*512-1
    Wqkv[i]              = (bf16)Wq[i];
    Wqkv[i + 262144]     = (bf16)Wk[i];
    Wqkv[i + 524288]     = (bf16)Wv[i];
    WoB[i]               = (bf16)Wo[i];
}

// ---------------- 3. fused mask+bias -> bf16, MFMA-C-fragment tiled, log2 domain -------
// storage: tile (ti,tj) base = (ti*NT+tj)*4096; within tile element (row,col) at
// p = (row>>2)*256 + (col&15)*16 + (col>>4)*4 + (row&3)
// => lane (w,lg,lc) of wave w reads its 16 frag elements [jt*4+r] contiguously.
__global__ void k_biasm(const int* __restrict__ adj, const float* __restrict__ gb,
                        bf16* __restrict__ biasT) {
    const int ti = blockIdx.x, tj = blockIdx.y;
    bf16* outp = biasT + ((size_t)ti * NT + tj) * 4096;
#pragma unroll
    for (int it = 0; it < 16; ++it) {
        const int p = it * 256 + threadIdx.x;
        const int row = ((p >> 8) << 2) + (p & 3);
        const int col = (((p >> 2) & 3) << 4) + ((p >> 4) & 15);
        const size_t src = (size_t)(ti * 64 + row) * Nn + tj * 64 + col;
        outp[p] = adj[src] ? (bf16)(gb[src] * 1.44269504f) : (bf16)(-1e30f);
    }
}

// ---------------- 4. QKV GEMM: feats[BN,512] x Wqkv[1536,512]^T -> Q,K [B,H,N,D], Vt [B,H,D,N]
__global__ __launch_bounds__(256) void k_qkv(
        const bf16* __restrict__ feats, const bf16* __restrict__ Wqkv,
        const float* __restrict__ bq, const float* __restrict__ bk, const float* __restrict__ bv,
        bf16* __restrict__ Q, bf16* __restrict__ K, bf16* __restrict__ Vt) {
    const int m0 = blockIdx.x * 64;
    const int n0 = blockIdx.y * 64;
    const int tid = threadIdx.x, w = tid >> 6, lane = tid & 63;
    const int lg = lane >> 4, lc = lane & 15;

    f32x4 acc[4];
    const f32x4 z4 = {0.f, 0.f, 0.f, 0.f};
#pragma unroll
    for (int jt = 0; jt < 4; ++jt) acc[jt] = z4;

    const bf16* arow = feats + (size_t)(m0 + w * 16 + lc) * Cc;
#pragma unroll 4
    for (int ks = 0; ks < 16; ++ks) {
        bf16x8 a = ldb8(arow + ks * 32 + lg * 8);
#pragma unroll
        for (int jt = 0; jt < 4; ++jt) {
            bf16x8 bb = ldb8(Wqkv + (size_t)(n0 + jt * 16 + lc) * Cc + ks * 32 + lg * 8);
            acc[jt] = __builtin_amdgcn_mfma_f32_16x16x32_bf16(a, bb, acc[jt], 0, 0, 0);
        }
    }

    const int proj = n0 >> 9;            // 0=q 1=k 2=v
    const int head = (n0 >> 6) & 7;
    const float* bias = proj == 0 ? bq : (proj == 1 ? bk : bv);
#pragma unroll
    for (int jt = 0; jt < 4; ++jt) {
        const int dcol = jt * 16 + lc;   // 0..63 == d within head
        const float bs = bias[(n0 & 511) + dcol];
#pragma unroll
        for (int r = 0; r < 4; ++r) {
            const int m = m0 + w * 16 + lg * 4 + r;
            const int b = m / Nn;
            const int n = m - b * Nn;
            const float v = acc[jt][r] + bs;
            if (proj == 0)
                Q[(((size_t)b * Hh + head) * Nn + n) * Dd + dcol] = (bf16)v;
            else if (proj == 1)
                K[(((size_t)b * Hh + head) * Nn + n) * Dd + dcol] = (bf16)v;
            else
                Vt[(((size_t)b * Hh + head) * Dd + dcol) * Nn + n] = (bf16)v;
        }
    }
}

// ---------------- 5. flash attention — barrier-free main loop ----------------
__global__ __launch_bounds__(256) void k_attn(
        const bf16* __restrict__ Q, const bf16* __restrict__ K, const bf16* __restrict__ Vt,
        const bf16* __restrict__ biasT, bf16* __restrict__ att) {
    __shared__ bf16 sP[4][16][72];       // per-wave region, no cross-wave sharing

    const int ti = blockIdx.x;
    const int i0 = ti * 64;
    const int bh = blockIdx.y;                 // b*8+h
    const int b = bh >> 3, h = bh & 7;
    const int tid = threadIdx.x, w = tid >> 6, lane = tid & 63;
    const int lg = lane >> 4, lc = lane & 15;

    const bf16* Qb = Q  + (size_t)bh * Nn * Dd;
    const bf16* Kb = K  + (size_t)bh * Nn * Dd;
    const bf16* Vb = Vt + (size_t)bh * Dd * Nn;
    // per-lane bias fragment base: 16 contiguous bf16 per tile
    const bf16* bp = biasT + (size_t)ti * NT * 4096 + (((w * 4 + lg) * 16 + lc) * 16);

    bf16x8 aq[2];
    {
        const bf16* qp = Qb + (size_t)(i0 + w * 16 + lc) * Dd + lg * 8;
        aq[0] = ldb8(qp);
        aq[1] = ldb8(qp + 32);
    }

    float mrow[4], lrow[4];
    f32x4 acc[4];
    const f32x4 z4 = {0.f, 0.f, 0.f, 0.f};
#pragma unroll
    for (int r = 0; r < 4; ++r) { mrow[r] = -1e30f; lrow[r] = 0.f; }
#pragma unroll
    for (int dj = 0; dj < 4; ++dj) acc[dj] = z4;

    constexpr float cqk = 0.18033688011112042f;   // 0.125 * log2(e)

    for (int tj = 0; tj < NT; ++tj) {
        const int j0 = tj * 64;
        // bias fragment (log2 domain), 2 coalesced 16B loads
        bf16x8 bb0 = ldb8(bp + (size_t)tj * 4096);
        bf16x8 bb1 = ldb8(bp + (size_t)tj * 4096 + 8);

        // S = Q K^T  (16q x 64k per wave)
        f32x4 s[4];
#pragma unroll
        for (int jt = 0; jt < 4; ++jt) s[jt] = z4;
#pragma unroll
        for (int jt = 0; jt < 4; ++jt) {
            const bf16* kp = Kb + (size_t)(j0 + jt * 16 + lc) * Dd + lg * 8;
            bf16x8 k0 = ldb8(kp);
            bf16x8 k1 = ldb8(kp + 32);
            s[jt] = __builtin_amdgcn_mfma_f32_16x16x32_bf16(aq[0], k0, s[jt], 0, 0, 0);
            s[jt] = __builtin_amdgcn_mfma_f32_16x16x32_bf16(aq[1], k1, s[jt], 0, 0, 0);
        }

        // val = s*0.125*log2e + bias*log2e   (all log2 domain)
        float sv[4][4];
#pragma unroll
        for (int jt = 0; jt < 4; ++jt)
#pragma unroll
            for (int r = 0; r < 4; ++r) {
                const float be = (float)(jt < 2 ? bb0[jt * 4 + r] : bb1[(jt - 2) * 4 + r]);
                sv[jt][r] = __builtin_fmaf(s[jt][r], cqk, be);
            }

        float tmax[4];
#pragma unroll
        for (int r = 0; r < 4; ++r) {
            float v = fmaxf(fmaxf(sv[0][r], sv[1][r]), fmaxf(sv[2][r], sv[3][r]));
            v = fmaxf(v, __shfl_xor(v, 1));
            v = fmaxf(v, __shfl_xor(v, 2));
            v = fmaxf(v, __shfl_xor(v, 4));
            v = fmaxf(v, __shfl_xor(v, 8));
            tmax[r] = v;
        }
        float scl[4];
#pragma unroll
        for (int r = 0; r < 4; ++r) {
            const float mn = fmaxf(mrow[r], tmax[r]);
            scl[r] = __builtin_amdgcn_exp2f(mrow[r] - mn);
            mrow[r] = mn;
        }
        float rsum[4] = {0.f, 0.f, 0.f, 0.f};
#pragma unroll
        for (int jt = 0; jt < 4; ++jt)
#pragma unroll
            for (int r = 0; r < 4; ++r) {
                float p = __builtin_amdgcn_exp2f(sv[jt][r] - mrow[r]);
                sv[jt][r] = p;
                rsum[r] += p;
            }
#pragma unroll
        for (int r = 0; r < 4; ++r) {
            float v = rsum[r];
            v += __shfl_xor(v, 1);
            v += __shfl_xor(v, 2);
            v += __shfl_xor(v, 4);
            v += __shfl_xor(v, 8);
            lrow[r] = lrow[r] * scl[r] + v;
#pragma unroll
            for (int dj = 0; dj < 4; ++dj) acc[dj][r] *= scl[r];
        }
        // write P (bf16) to per-wave LDS (same-wave visibility: lgkmcnt only)
#pragma unroll
        for (int jt = 0; jt < 4; ++jt)
#pragma unroll
            for (int r = 0; r < 4; ++r)
                sP[w][lg * 4 + r][jt * 16 + lc] = (bf16)sv[jt][r];

        // acc += P V   (A = P[16x32], B = Vt)
#pragma unroll
        for (int ks = 0; ks < 2; ++ks) {
            bf16x8 pa = *reinterpret_cast<const bf16x8*>(&sP[w][lc][ks * 32 + lg * 8]);
#pragma unroll
            for (int dj = 0; dj < 4; ++dj) {
                const bf16* vp = Vb + (size_t)(dj * 16 + lc) * Nn + j0 + ks * 32 + lg * 8;
                bf16x8 bv = ldb8(vp);
                acc[dj] = __builtin_amdgcn_mfma_f32_16x16x32_bf16(pa, bv, acc[dj], 0, 0, 0);
            }
        }
    }

#pragma unroll
    for (int r = 0; r < 4; ++r) {
        const float inv = 1.f / lrow[r];
        const int n = i0 + w * 16 + lg * 4 + r;
#pragma unroll
        for (int dj = 0; dj < 4; ++dj)
            att[((size_t)b * Nn + n) * Cc + h * 64 + dj * 16 + lc] = (bf16)(acc[dj][r] * inv);
    }
}

// ---------------- 6. out GEMM: att[BN,512] x Wo^T + bo -> out [B,C,N] ----------------
__global__ __launch_bounds__(256) void k_out(
        const bf16* __restrict__ att, const bf16* __restrict__ WoB,
        const float* __restrict__ bo, float* __restrict__ out) {
    const int m0 = blockIdx.x * 64;
    const int n0 = blockIdx.y * 64;
    const int tid = threadIdx.x, w = tid >> 6, lane = tid & 63;
    const int lg = lane >> 4, lc = lane & 15;

    f32x4 acc[4];
    const f32x4 z4 = {0.f, 0.f, 0.f, 0.f};
#pragma unroll
    for (int jt = 0; jt < 4; ++jt) acc[jt] = z4;

    const bf16* arow = att + (size_t)(m0 + w * 16 + lc) * Cc;
#pragma unroll 4
    for (int ks = 0; ks < 16; ++ks) {
        bf16x8 a = ldb8(arow + ks * 32 + lg * 8);
#pragma unroll
        for (int jt = 0; jt < 4; ++jt) {
            bf16x8 bb = ldb8(WoB + (size_t)(n0 + jt * 16 + lc) * Cc + ks * 32 + lg * 8);
            acc[jt] = __builtin_amdgcn_mfma_f32_16x16x32_bf16(a, bb, acc[jt], 0, 0, 0);
        }
    }

    const int m = m0 + w * 16 + lg * 4;   // 4 consecutive n per lane
    const int b = m / Nn;
    const int n = m - b * Nn;
#pragma unroll
    for (int jt = 0; jt < 4; ++jt) {
        const int col = n0 + jt * 16 + lc;
        const float bs = bo[col];
        f32x4 vv;
#pragma unroll
        for (int r = 0; r < 4; ++r) vv[r] = acc[jt][r] + bs;
        *reinterpret_cast<f32x4*>(&out[((size_t)b * Cc + col) * Nn + n]) = vv;
    }
}

// ---------------- launch ----------------
extern "C" void kernel_launch(void* const* d_in, const int* in_sizes, int n_in,
                              void* d_out, int out_size, void* d_ws, size_t ws_size,
                              hipStream_t stream) {
    (void)in_sizes; (void)n_in; (void)out_size; (void)ws_size;
    const float* x  = (const float*)d_in[0];
    const int*   adj= (const int*)d_in[1];
    const float* gb = (const float*)d_in[2];
    const float* Wq = (const float*)d_in[3];
    const float* bq = (const float*)d_in[4];
    const float* Wk = (const float*)d_in[5];
    const float* bk = (const float*)d_in[6];
    const float* Wv = (const float*)d_in[7];
    const float* bv = (const float*)d_in[8];
    const float* Wo = (const float*)d_in[9];
    const float* bo = (const float*)d_in[10];
    float* out = (float*)d_out;

    char* ws = (char*)d_ws;
    bf16* feats = (bf16*)(ws);                    // 6,291,456 B
    bf16* Wqkv  = (bf16*)(ws + 6291456);          // 1,572,864 B
    bf16* WoB   = (bf16*)(ws + 7864320);          //   524,288 B
    bf16* Qm    = (bf16*)(ws + 8388608);          // 6,291,456 B
    bf16* Km    = (bf16*)(ws + 14680064);         // 6,291,456 B
    bf16* Vt    = (bf16*)(ws + 20971520);         // 6,291,456 B
    bf16* att   = (bf16*)(ws + 27262976);         // 6,291,456 B
    bf16* biasT = (bf16*)(ws + 33554432);         // 18,874,368 B  (total 50 MB)

    k_tx   <<<dim3(Nn / 32, Cc / 32, Bb), dim3(32, 8), 0, stream>>>(x, feats);
    k_packw<<<dim3(1024), dim3(256), 0, stream>>>(Wq, Wk, Wv, Wo, Wqkv, WoB);
    k_biasm<<<dim3(NT, NT), dim3(256), 0, stream>>>(adj, gb, biasT);
    k_qkv  <<<dim3(BN / 64, 1536 / 64), dim3(256), 0, stream>>>(feats, Wqkv, bq, bk, bv, Qm, Km, Vt);
    k_attn <<<dim3(NT, Bb * Hh), dim3(256), 0, stream>>>(Qm, Km, Vt, biasT, att);
    k_out  <<<dim3(BN / 64, Cc / 64), dim3(256), 0, stream>>>(att, WoB, bo, out);
}

// Round 3
// 283.950 us; speedup vs baseline: 1.4900x; 1.4685x over previous
//
#include <hip/hip_runtime.h>

constexpr int Bb = 2, Cc = 512, Nn = 3072, Hh = 8, Dd = 64;
constexpr int BN = Bb * Nn;
constexpr int NT = Nn / 64;   // 48 tiles per dim

typedef __bf16 bf16;
typedef __attribute__((ext_vector_type(8))) __bf16 bf16x8;
typedef __attribute__((ext_vector_type(4))) float f32x4;

#define DEVINL static __device__ __forceinline__

DEVINL bf16x8 ldb8(const bf16* p) { return *reinterpret_cast<const bf16x8*>(p); }

DEVINL void gload_lds16(const bf16* g, bf16* l) {
    __builtin_amdgcn_global_load_lds(
        (const __attribute__((address_space(1))) void*)g,
        (__attribute__((address_space(3))) void*)l, 16, 0, 0);
}

// ---------------- 1. transpose + cast x [B,C,N] -> feats [B,N,C] bf16 ----------------
__global__ void k_tx(const float* __restrict__ x, bf16* __restrict__ feats) {
    __shared__ float t[32][33];
    const int b = blockIdx.z;
    const int n0 = blockIdx.x * 32, c0 = blockIdx.y * 32;
    const int tx = threadIdx.x, ty = threadIdx.y;   // 32 x 8
#pragma unroll
    for (int i = 0; i < 4; ++i)
        t[ty + i * 8][tx] = x[((size_t)b * Cc + c0 + ty + i * 8) * Nn + n0 + tx];
    __syncthreads();
#pragma unroll
    for (int i = 0; i < 4; ++i)
        feats[((size_t)b * Nn + n0 + ty + i * 8) * Cc + c0 + tx] = (bf16)t[tx][ty + i * 8];
}

// ---------------- 2. pack weights to bf16 ----------------
__global__ void k_packw(const float* __restrict__ Wq, const float* __restrict__ Wk,
                        const float* __restrict__ Wv, const float* __restrict__ Wo,
                        bf16* __restrict__ Wqkv, bf16* __restrict__ WoB) {
    const int i = blockIdx.x * 256 + threadIdx.x;   // 0 .. 512*512-1
    Wqkv[i]              = (bf16)Wq[i];
    Wqkv[i + 262144]     = (bf16)Wk[i];
    Wqkv[i + 524288]     = (bf16)Wv[i];
    WoB[i]               = (bf16)Wo[i];
}

// ---------------- 3. fused mask+bias -> bf16, MFMA-C-fragment tiled, log2 domain -------
__global__ void k_biasm(const int* __restrict__ adj, const float* __restrict__ gb,
                        bf16* __restrict__ biasT) {
    const int ti = blockIdx.x, tj = blockIdx.y;
    bf16* outp = biasT + ((size_t)ti * NT + tj) * 4096;
#pragma unroll
    for (int it = 0; it < 16; ++it) {
        const int p = it * 256 + threadIdx.x;
        const int row = ((p >> 8) << 2) + (p & 3);
        const int col = (((p >> 2) & 3) << 4) + ((p >> 4) & 15);
        const size_t src = (size_t)(ti * 64 + row) * Nn + tj * 64 + col;
        outp[p] = adj[src] ? (bf16)(gb[src] * 1.44269504f) : (bf16)(-1e30f);
    }
}

// ---------------- 4. QKV GEMM ----------------
__global__ __launch_bounds__(256) void k_qkv(
        const bf16* __restrict__ feats, const bf16* __restrict__ Wqkv,
        const float* __restrict__ bq, const float* __restrict__ bk, const float* __restrict__ bv,
        bf16* __restrict__ Q, bf16* __restrict__ K, bf16* __restrict__ Vt) {
    const int m0 = blockIdx.x * 64;
    const int n0 = blockIdx.y * 64;
    const int tid = threadIdx.x, w = tid >> 6, lane = tid & 63;
    const int lg = lane >> 4, lc = lane & 15;

    f32x4 acc[4];
    const f32x4 z4 = {0.f, 0.f, 0.f, 0.f};
#pragma unroll
    for (int jt = 0; jt < 4; ++jt) acc[jt] = z4;

    const bf16* arow = feats + (size_t)(m0 + w * 16 + lc) * Cc;
#pragma unroll 4
    for (int ks = 0; ks < 16; ++ks) {
        bf16x8 a = ldb8(arow + ks * 32 + lg * 8);
#pragma unroll
        for (int jt = 0; jt < 4; ++jt) {
            bf16x8 bb = ldb8(Wqkv + (size_t)(n0 + jt * 16 + lc) * Cc + ks * 32 + lg * 8);
            acc[jt] = __builtin_amdgcn_mfma_f32_16x16x32_bf16(a, bb, acc[jt], 0, 0, 0);
        }
    }

    const int proj = n0 >> 9;            // 0=q 1=k 2=v
    const int head = (n0 >> 6) & 7;
    const float* bias = proj == 0 ? bq : (proj == 1 ? bk : bv);
#pragma unroll
    for (int jt = 0; jt < 4; ++jt) {
        const int dcol = jt * 16 + lc;
        const float bs = bias[(n0 & 511) + dcol];
#pragma unroll
        for (int r = 0; r < 4; ++r) {
            const int m = m0 + w * 16 + lg * 4 + r;
            const int b = m / Nn;
            const int n = m - b * Nn;
            const float v = acc[jt][r] + bs;
            if (proj == 0)
                Q[(((size_t)b * Hh + head) * Nn + n) * Dd + dcol] = (bf16)v;
            else if (proj == 1)
                K[(((size_t)b * Hh + head) * Nn + n) * Dd + dcol] = (bf16)v;
            else
                Vt[(((size_t)b * Hh + head) * Dd + dcol) * Nn + n] = (bf16)v;
        }
    }
}

// ---------------- 5. flash attention — LDS-staged K/V, 2-phase pipeline ----------------
__global__ __launch_bounds__(256) void k_attn(
        const bf16* __restrict__ Q, const bf16* __restrict__ K, const bf16* __restrict__ Vt,
        const bf16* __restrict__ biasT, bf16* __restrict__ att) {
    __shared__ bf16 sK[2][4096];   // 64 rows x 64 cols, xor-swizzled col-blocks
    __shared__ bf16 sV[2][4096];   // 64 d-rows x 64 j-cols, same swizzle
    __shared__ bf16 sP[4][16][72];

    const int ti = blockIdx.x;
    const int i0 = ti * 64;
    const int bh = blockIdx.y;                 // b*8+h
    const int b = bh >> 3, h = bh & 7;
    const int tid = threadIdx.x, w = tid >> 6, lane = tid & 63;
    const int lg = lane >> 4, lc = lane & 15;

    const bf16* Qb = Q  + (size_t)bh * Nn * Dd;
    const bf16* Kb = K  + (size_t)bh * Nn * Dd;
    const bf16* Vb = Vt + (size_t)bh * Dd * Nn;
    const bf16* bp = biasT + (size_t)ti * NT * 4096 + (((w * 4 + lg) * 16 + lc) * 16);

    bf16x8 aq[2];
    {
        const bf16* qp = Qb + (size_t)(i0 + w * 16 + lc) * Dd + lg * 8;
        aq[0] = ldb8(qp);
        aq[1] = ldb8(qp + 32);
    }

    float mrow[4], lrow[4];
    f32x4 acc[4];
    const f32x4 z4 = {0.f, 0.f, 0.f, 0.f};
#pragma unroll
    for (int r = 0; r < 4; ++r) { mrow[r] = -1e30f; lrow[r] = 0.f; }
#pragma unroll
    for (int dj = 0; dj < 4; ++dj) acc[dj] = z4;

    constexpr float cqk = 0.18033688011112042f;   // 0.125 * log2(e)

    // per-lane staging slots: s = (2w+it)*64 + lane; inverse-swizzled global source
    // stage K/V tile j0 into buffer `bi` (4 global_load_lds per wave)
#define STAGE(bi, j0)                                                              \
    {                                                                              \
        _Pragma("unroll")                                                          \
        for (int it = 0; it < 2; ++it) {                                           \
            const int s = w * 128 + it * 64 + lane;                                \
            const int pr = s >> 3, pcb = s & 7;                                    \
            const int cb = (pcb ^ (pr & 7)) * 8;                                   \
            gload_lds16(Kb + (size_t)((j0) + pr) * Dd + cb,                        \
                        &sK[bi][(w * 2 + it) * 512]);                              \
            gload_lds16(Vb + (size_t)pr * Nn + (j0) + cb,                          \
                        &sV[bi][(w * 2 + it) * 512]);                              \
        }                                                                          \
    }

    int buf = 0;
    STAGE(0, 0);
    bf16x8 bc0 = ldb8(bp);
    bf16x8 bc1 = ldb8(bp + 8);

    for (int tj = 0; tj < NT; ++tj) {
        const int tjn = (tj + 1 < NT) ? tj + 1 : NT - 1;   // clamp: uniform vmcnt count
        STAGE(buf ^ 1, tjn * 64);
        bf16x8 bn0 = ldb8(bp + (size_t)tjn * 4096);
        bf16x8 bn1 = ldb8(bp + (size_t)tjn * 4096 + 8);

        // wait: current tile's 4 staging loads (+its bias) done; 6 newest stay in flight
        asm volatile("s_waitcnt vmcnt(6)" ::: "memory");
        __builtin_amdgcn_s_barrier();

        // S = Q K^T  (16q x 64k per wave) from swizzled LDS
        f32x4 s4[4];
#pragma unroll
        for (int jt = 0; jt < 4; ++jt) s4[jt] = z4;
#pragma unroll
        for (int jt = 0; jt < 4; ++jt) {
            const int r = jt * 16 + lc;
            bf16x8 k0 = ldb8(&sK[buf][r * 64 + ((lg ^ (r & 7)) * 8)]);
            bf16x8 k1 = ldb8(&sK[buf][r * 64 + (((lg + 4) ^ (r & 7)) * 8)]);
            s4[jt] = __builtin_amdgcn_mfma_f32_16x16x32_bf16(aq[0], k0, s4[jt], 0, 0, 0);
            s4[jt] = __builtin_amdgcn_mfma_f32_16x16x32_bf16(aq[1], k1, s4[jt], 0, 0, 0);
        }

        // val = s*0.125*log2e + bias (log2 domain)
        float sv[4][4];
#pragma unroll
        for (int jt = 0; jt < 4; ++jt)
#pragma unroll
            for (int r = 0; r < 4; ++r) {
                const float be = (float)(jt < 2 ? bc0[jt * 4 + r] : bc1[(jt - 2) * 4 + r]);
                sv[jt][r] = __builtin_fmaf(s4[jt][r], cqk, be);
            }

        float tmax[4];
#pragma unroll
        for (int r = 0; r < 4; ++r) {
            float v = fmaxf(fmaxf(sv[0][r], sv[1][r]), fmaxf(sv[2][r], sv[3][r]));
            v = fmaxf(v, __shfl_xor(v, 1));
            v = fmaxf(v, __shfl_xor(v, 2));
            v = fmaxf(v, __shfl_xor(v, 4));
            v = fmaxf(v, __shfl_xor(v, 8));
            tmax[r] = v;
        }
        float scl[4];
#pragma unroll
        for (int r = 0; r < 4; ++r) {
            const float mn = fmaxf(mrow[r], tmax[r]);
            scl[r] = __builtin_amdgcn_exp2f(mrow[r] - mn);
            mrow[r] = mn;
        }
        float rsum[4] = {0.f, 0.f, 0.f, 0.f};
#pragma unroll
        for (int jt = 0; jt < 4; ++jt)
#pragma unroll
            for (int r = 0; r < 4; ++r) {
                float p = __builtin_amdgcn_exp2f(sv[jt][r] - mrow[r]);
                sv[jt][r] = p;
                rsum[r] += p;
            }
#pragma unroll
        for (int r = 0; r < 4; ++r) {
            float v = rsum[r];
            v += __shfl_xor(v, 1);
            v += __shfl_xor(v, 2);
            v += __shfl_xor(v, 4);
            v += __shfl_xor(v, 8);
            lrow[r] = lrow[r] * scl[r] + v;
#pragma unroll
            for (int dj = 0; dj < 4; ++dj) acc[dj][r] *= scl[r];
        }
        // write P to per-wave LDS (same-wave visibility: lgkmcnt only)
#pragma unroll
        for (int jt = 0; jt < 4; ++jt)
#pragma unroll
            for (int r = 0; r < 4; ++r)
                sP[w][lg * 4 + r][jt * 16 + lc] = (bf16)sv[jt][r];

        // acc += P V  from swizzled LDS V tile
#pragma unroll
        for (int ks = 0; ks < 2; ++ks) {
            bf16x8 pa = *reinterpret_cast<const bf16x8*>(&sP[w][lc][ks * 32 + lg * 8]);
#pragma unroll
            for (int dj = 0; dj < 4; ++dj) {
                const int rv = dj * 16 + lc;
                bf16x8 bv = ldb8(&sV[buf][rv * 64 + (((ks * 4 + lg) ^ (rv & 7)) * 8)]);
                acc[dj] = __builtin_amdgcn_mfma_f32_16x16x32_bf16(pa, bv, acc[dj], 0, 0, 0);
            }
        }

        // all waves done reading buf before next iteration overwrites the other half
        __builtin_amdgcn_s_barrier();
        bc0 = bn0; bc1 = bn1;
        buf ^= 1;
    }

    // LDS-DMA must not outlive the block
    asm volatile("s_waitcnt vmcnt(0)" ::: "memory");

#pragma unroll
    for (int r = 0; r < 4; ++r) {
        const float inv = 1.f / lrow[r];
        const int n = i0 + w * 16 + lg * 4 + r;
#pragma unroll
        for (int dj = 0; dj < 4; ++dj)
            att[((size_t)b * Nn + n) * Cc + h * 64 + dj * 16 + lc] = (bf16)(acc[dj][r] * inv);
    }
#undef STAGE
}

// ---------------- 6. out GEMM: att[BN,512] x Wo^T + bo -> out [B,C,N] ----------------
__global__ __launch_bounds__(256) void k_out(
        const bf16* __restrict__ att, const bf16* __restrict__ WoB,
        const float* __restrict__ bo, float* __restrict__ out) {
    const int m0 = blockIdx.x * 64;
    const int n0 = blockIdx.y * 64;
    const int tid = threadIdx.x, w = tid >> 6, lane = tid & 63;
    const int lg = lane >> 4, lc = lane & 15;

    f32x4 acc[4];
    const f32x4 z4 = {0.f, 0.f, 0.f, 0.f};
#pragma unroll
    for (int jt = 0; jt < 4; ++jt) acc[jt] = z4;

    const bf16* arow = att + (size_t)(m0 + w * 16 + lc) * Cc;
#pragma unroll 4
    for (int ks = 0; ks < 16; ++ks) {
        bf16x8 a = ldb8(arow + ks * 32 + lg * 8);
#pragma unroll
        for (int jt = 0; jt < 4; ++jt) {
            bf16x8 bb = ldb8(WoB + (size_t)(n0 + jt * 16 + lc) * Cc + ks * 32 + lg * 8);
            acc[jt] = __builtin_amdgcn_mfma_f32_16x16x32_bf16(a, bb, acc[jt], 0, 0, 0);
        }
    }

    const int m = m0 + w * 16 + lg * 4;
    const int b = m / Nn;
    const int n = m - b * Nn;
#pragma unroll
    for (int jt = 0; jt < 4; ++jt) {
        const int col = n0 + jt * 16 + lc;
        const float bs = bo[col];
        f32x4 vv;
#pragma unroll
        for (int r = 0; r < 4; ++r) vv[r] = acc[jt][r] + bs;
        *reinterpret_cast<f32x4*>(&out[((size_t)b * Cc + col) * Nn + n]) = vv;
    }
}

// ---------------- launch ----------------
extern "C" void kernel_launch(void* const* d_in, const int* in_sizes, int n_in,
                              void* d_out, int out_size, void* d_ws, size_t ws_size,
                              hipStream_t stream) {
    (void)in_sizes; (void)n_in; (void)out_size; (void)ws_size;
    const float* x  = (const float*)d_in[0];
    const int*   adj= (const int*)d_in[1];
    const float* gb = (const float*)d_in[2];
    const float* Wq = (const float*)d_in[3];
    const float* bq = (const float*)d_in[4];
    const float* Wk = (const float*)d_in[5];
    const float* bk = (const float*)d_in[6];
    const float* Wv = (const float*)d_in[7];
    const float* bv = (const float*)d_in[8];
    const float* Wo = (const float*)d_in[9];
    const float* bo = (const float*)d_in[10];
    float* out = (float*)d_out;

    char* ws = (char*)d_ws;
    bf16* feats = (bf16*)(ws);                    // 6,291,456 B
    bf16* Wqkv  = (bf16*)(ws + 6291456);          // 1,572,864 B
    bf16* WoB   = (bf16*)(ws + 7864320);          //   524,288 B
    bf16* Qm    = (bf16*)(ws + 8388608);          // 6,291,456 B
    bf16* Km    = (bf16*)(ws + 14680064);         // 6,291,456 B
    bf16* Vt    = (bf16*)(ws + 20971520);         // 6,291,456 B
    bf16* att   = (bf16*)(ws + 27262976);         // 6,291,456 B
    bf16* biasT = (bf16*)(ws + 33554432);         // 18,874,368 B  (total 50 MB)

    k_tx   <<<dim3(Nn / 32, Cc / 32, Bb), dim3(32, 8), 0, stream>>>(x, feats);
    k_packw<<<dim3(1024), dim3(256), 0, stream>>>(Wq, Wk, Wv, Wo, Wqkv, WoB);
    k_biasm<<<dim3(NT, NT), dim3(256), 0, stream>>>(adj, gb, biasT);
    k_qkv  <<<dim3(BN / 64, 1536 / 64), dim3(256), 0, stream>>>(feats, Wqkv, bq, bk, bv, Qm, Km, Vt);
    k_attn <<<dim3(NT, Bb * Hh), dim3(256), 0, stream>>>(Qm, Km, Vt, biasT, att);
    k_out  <<<dim3(BN / 64, Cc / 64), dim3(256), 0, stream>>>(att, WoB, bo, out);
}